// Round 6
// baseline (1355.564 us; speedup 1.0000x reference)
//
#include <hip/hip_runtime.h>
#include <stdint.h>
#include <math.h>

#define NB      8
#define NPTS    16384
#define NPOINT  512
#define NCH     128
#define KNBR    32
#define R2      0.04f

#define FPSB    8                   // FPS blocks per batch
#define FPSPTS  (NPTS / FPSB)       // 2048 points per block
#define FPST    256                 // threads per FPS block
#define FPSK    (FPSPTS / FPST)     // 8 points per thread

typedef unsigned long long u64;

// argmax step over (value desc, index asc) using DPP permute (VALU latency)
#define DPP_ARG_STEP(v, p, CTRL) do {                                          \
    float _ov = __builtin_bit_cast(float, __builtin_amdgcn_update_dpp(         \
        __builtin_bit_cast(int, (v)), __builtin_bit_cast(int, (v)),            \
        (CTRL), 0xF, 0xF, false));                                             \
    int _op = __builtin_amdgcn_update_dpp((p), (p), (CTRL), 0xF, 0xF, false);  \
    bool _t = (_ov > (v)) || ((_ov == (v)) && (_op < (p)));                    \
    (v) = _t ? _ov : (v);                                                      \
    (p) = _t ? _op : (p);                                                      \
} while (0)

#define SHFL_ARG_STEP(v, p, XORAMT) do {                                       \
    float _ov = __shfl_xor((v), (XORAMT), 64);                                 \
    int   _op = __shfl_xor((p), (XORAMT), 64);                                 \
    bool _t = (_ov > (v)) || ((_ov == (v)) && (_op < (p)));                    \
    (v) = _t ? _ov : (v);                                                      \
    (p) = _t ? _op : (p);                                                      \
} while (0)

// uint comparator step for cross-block winner (value bits desc, index asc)
#define SHFL_ARG_STEP_U(v, p, XORAMT) do {                                     \
    unsigned _ov = __shfl_xor((v), (XORAMT), 64);                              \
    unsigned _op = __shfl_xor((p), (XORAMT), 64);                              \
    bool _t = (_ov > (v)) || ((_ov == (v)) && (_op < (p)));                    \
    (v) = _t ? _ov : (v);                                                      \
    (p) = _t ? _op : (p);                                                      \
} while (0)

// -------- kernel 1: multi-block FPS (blocks 0..63) + feature transpose ------
// 8 blocks/batch, 8 pts/thread, register-resident. Cross-block handshake via
// PARITY-DOUBLE-BUFFERED u64 slots: iteration i publishes to slots[i&1].
// A block can only overwrite a buffer (tag i+2, same parity as i) after ALL
// blocks passed the poll at i+1, which requires all blocks consumed buffer
// i&1 — so tag-i values are never destroyed while needed, and a poller at i
// can never observe a future tag in its buffer. Payload (value|iter|index)
// lives inside the single atomic u64 -> relaxed agent-scope, no fences.
__global__ __launch_bounds__(FPST, 2)
void fps_transpose_kernel(const float* __restrict__ xyz,
                          const float* __restrict__ feat,
                          float* __restrict__ out,     // new_xyz at [0,12288)
                          int* __restrict__ cent,      // ws: 8*512 ints
                          u64* __restrict__ slots,     // ws: 2*8*8 u64
                          float* __restrict__ ft,      // ws: (B,N,128) fp32
                          int use_ft)
{
    const int blk = blockIdx.x;
    const int tid = threadIdx.x;

    if (blk < NB * FPSB) {
        const int b = blk >> 3;        // batch
        const int j = blk & 7;         // sub-block within batch
        const int base = j * FPSPTS;
        const float* xb = xyz + (size_t)b * NPTS * 3;
        // slots layout: [parity][batch][block]
        u64* bs0 = slots + 0 * NB * FPSB + b * FPSB;
        u64* bs1 = slots + 1 * NB * FPSB + b * FPSB;

        float px[FPSK], py[FPSK], pz[FPSK], dist[FPSK];
#pragma unroll
        for (int k = 0; k < FPSK; ++k) {
            int p = base + k * FPST + tid;
            px[k] = xb[p * 3 + 0];
            py[k] = xb[p * 3 + 1];
            pz[k] = xb[p * 3 + 2];
            dist[k] = 1e10f;
        }
        __shared__ float s_v[2][4];
        __shared__ int   s_p[2][4];
        const int lane = tid & 63;
        const int wid  = tid >> 6;

        float cx = xb[0], cy = xb[1], cz = xb[2];
        if (j == 0 && tid == 0) {
            cent[b * NPOINT + 0] = 0;
            out[((size_t)b * NPOINT + 0) * 3 + 0] = cx;
            out[((size_t)b * NPOINT + 0) * 3 + 1] = cy;
            out[((size_t)b * NPOINT + 0) * 3 + 2] = cz;
        }

        for (int i = 1; i < NPOINT; ++i) {
            float bv = -1.0f; int bk = 0;
#pragma unroll
            for (int k = 0; k < FPSK; ++k) {
                float dx = __fsub_rn(px[k], cx);
                float dy = __fsub_rn(py[k], cy);
                float dz = __fsub_rn(pz[k], cz);
                float d  = __fadd_rn(__fadd_rn(__fmul_rn(dx, dx),
                                               __fmul_rn(dy, dy)),
                                     __fmul_rn(dz, dz));
                float nd = fminf(dist[k], d);   // np.minimum, exact
                dist[k] = nd;
                if (nd > bv) { bv = nd; bk = k; }  // strict >: earliest k wins
            }
            float rv = bv;
            int   rp = base + bk * FPST + tid;   // global point index
            DPP_ARG_STEP(rv, rp, 0xB1);
            DPP_ARG_STEP(rv, rp, 0x4E);
            DPP_ARG_STEP(rv, rp, 0x141);
            DPP_ARG_STEP(rv, rp, 0x140);
            SHFL_ARG_STEP(rv, rp, 16);
            SHFL_ARG_STEP(rv, rp, 32);
            const int buf = i & 1;
            u64* bslots = buf ? bs1 : bs0;
            if (lane == 0) { s_v[buf][wid] = rv; s_p[buf][wid] = rp; }
            __syncthreads();   // partials visible (double-buffered in LDS too)
            float fv = s_v[buf][lane & 3];
            int   fp = s_p[buf][lane & 3];
            DPP_ARG_STEP(fv, fp, 0xB1);
            DPP_ARG_STEP(fv, fp, 0x4E);
            // publish this block's winner into the parity buffer
            if (tid == 0) {
                u64 pk = ((u64)__builtin_bit_cast(unsigned, fv) << 32)
                       | (u64)(((unsigned)i << 14) | (unsigned)fp);
                __hip_atomic_store(&bslots[j], pk, __ATOMIC_RELAXED,
                                   __HIP_MEMORY_SCOPE_AGENT);
            }
            // poll all 8 slots of this parity for tag == i (exact match is
            // safe: a future tag of same parity cannot appear, see header)
            const int jj = lane & 7;
            u64 got = 0;
            int guard = 0;
            for (;;) {
                got = __hip_atomic_load(&bslots[jj], __ATOMIC_RELAXED,
                                        __HIP_MEMORY_SCOPE_AGENT);
                bool ok = (((unsigned)got) >> 14) == (unsigned)i;
                if (__ballot(ok) == ~0ull) break;
                if (++guard > (1 << 20)) break;   // never hang the harness
            }
            unsigned wv = (unsigned)(got >> 32);
            unsigned wp = (unsigned)got & 0x3FFFu;
            // reduce the 8 block winners (nonneg fp32: uint order == fp order)
            SHFL_ARG_STEP_U(wv, wp, 1);
            SHFL_ARG_STEP_U(wv, wp, 2);
            SHFL_ARG_STEP_U(wv, wp, 4);
            const int cur = (int)__builtin_amdgcn_readfirstlane(wp);
            cx = xb[cur * 3 + 0];   // uniform (scalar) reload, L2-hot
            cy = xb[cur * 3 + 1];
            cz = xb[cur * 3 + 2];
            if (j == 0 && tid == 0) {
                cent[b * NPOINT + i] = cur;
                size_t o = ((size_t)b * NPOINT + i) * 3;
                out[o + 0] = cx; out[o + 1] = cy; out[o + 2] = cz;
            }
        }
    } else {
        if (!use_ft) return;
        // transpose feat (B,128,N) -> ft (B,N,128): 32x32 tiles, 256 thr,
        // 4 elements per thread
        int t  = blk - NB * FPSB;
        int b  = t >> 11;          // 2048 tiles per batch
        int r  = t & 2047;
        int ct = r >> 9;           // channel tile (4)
        int nt = r & 511;          // point tile (512)
        __shared__ float tile[32][33];
        int tx = tid & 31, ty = tid >> 5;   // ty in [0,8)
        int n = nt * 32 + tx;
#pragma unroll
        for (int rr = 0; rr < 4; ++rr) {
            int c = ct * 32 + ty + rr * 8;
            tile[ty + rr * 8][tx] = feat[((size_t)b * NCH + c) * NPTS + n];
        }
        __syncthreads();
        int c2 = ct * 32 + tx;
#pragma unroll
        for (int rr = 0; rr < 4; ++rr) {
            int n2 = nt * 32 + ty + rr * 8;
            ft[((size_t)b * NPTS + n2) * NCH + c2] = tile[tx][ty + rr * 8];
        }
    }
}

// -------- kernel 2: ball query + grouped max pool ---------------------------
__global__ __launch_bounds__(256, 4)
void query_pool_kernel(const float* __restrict__ xyz,
                       const float* __restrict__ feat,
                       const float* __restrict__ ft,
                       const int* __restrict__ cent,
                       float* __restrict__ out_sub,   // (B,128,512)
                       int use_ft)
{
    const int tid  = threadIdx.x;
    const int widx = tid >> 6;
    const int lane = tid & 63;
    const int w = blockIdx.x * 4 + widx;   // 0..4095
    const int b = w >> 9;
    const int s = w & 511;

    const float* xb = xyz + (size_t)b * NPTS * 3;
    const int ci = cent[b * NPOINT + s];
    const float sx = xb[ci * 3 + 0];
    const float sy = xb[ci * 3 + 1];
    const float sz = xb[ci * 3 + 2];
    const float snorm = __fadd_rn(__fadd_rn(__fmul_rn(sx, sx),
                                            __fmul_rn(sy, sy)),
                                  __fmul_rn(sz, sz));

    __shared__ int lidx[4][KNBR];
    int found = 0;
    for (int base = 0; base < NPTS && found < KNBR; base += 64) {
        int j = base + lane;
        float dx = xb[j * 3 + 0];
        float dy = xb[j * 3 + 1];
        float dz = xb[j * 3 + 2];
        float dn = __fadd_rn(__fadd_rn(__fmul_rn(dx, dx),
                                       __fmul_rn(dy, dy)),
                             __fmul_rn(dz, dz));
        float dot = __fadd_rn(__fadd_rn(__fmul_rn(sx, dx),
                                        __fmul_rn(sy, dy)),
                              __fmul_rn(sz, dz));
        float d = __fadd_rn(__fadd_rn(__fmul_rn(-2.0f, dot), snorm), dn);
        bool inball = !(d > R2);
        unsigned long long mask = __ballot(inball);
        int before = (int)__popcll(mask & ((1ULL << lane) - 1ULL));
        int slot = found + before;
        if (inball && slot < KNBR) lidx[widx][slot] = j;
        found += (int)__popcll(mask);
    }
    int cnt = found < KNBR ? found : KNBR;   // cnt >= 1 (self in ball)
    __syncthreads();

    float a0 = -INFINITY, a1 = -INFINITY;
    if (use_ft) {
        for (int m = 0; m < cnt; ++m) {
            int i = lidx[widx][m];
            const float* row = ft + ((size_t)b * NPTS + i) * NCH;
            a0 = fmaxf(a0, row[lane]);
            a1 = fmaxf(a1, row[lane + 64]);
        }
    } else {
        for (int m = 0; m < cnt; ++m) {
            int i = lidx[widx][m];
            a0 = fmaxf(a0, feat[((size_t)b * NCH + lane) * NPTS + i]);
            a1 = fmaxf(a1, feat[((size_t)b * NCH + lane + 64) * NPTS + i]);
        }
    }
    out_sub[((size_t)b * NCH + lane) * NPOINT + s] = a0;
    out_sub[((size_t)b * NCH + lane + 64) * NPOINT + s] = a1;
}

extern "C" void kernel_launch(void* const* d_in, const int* in_sizes, int n_in,
                              void* d_out, int out_size, void* d_ws, size_t ws_size,
                              hipStream_t stream)
{
    const float* xyz  = (const float*)d_in[0];   // (8,16384,3)
    const float* feat = (const float*)d_in[1];   // (8,128,16384)
    float* out = (float*)d_out;                  // [new_xyz | sub_features]

    int*   cent  = (int*)d_ws;                             // 16 KB
    u64*   slots = (u64*)((char*)d_ws + 16384);            // 1 KB (2 parities)
    float* ft    = (float*)((char*)d_ws + 32768);          // 67 MB transposed
    const size_t need_ft = 32768ull + (size_t)NB * NPTS * NCH * 4ull;
    int use_ft = (ws_size >= need_ft) ? 1 : 0;

    int nblocks1 = NB * FPSB + (use_ft ? NB * (NCH / 32) * (NPTS / 32) : 0);
    hipLaunchKernelGGL(fps_transpose_kernel, dim3(nblocks1), dim3(FPST), 0, stream,
                       xyz, feat, out, cent, slots, ft, use_ft);

    hipLaunchKernelGGL(query_pool_kernel, dim3((NB * NPOINT) / 4), dim3(256), 0, stream,
                       xyz, feat, ft, cent, out + (size_t)NB * NPOINT * 3, use_ft);
}

// Round 7
// 1227.933 us; speedup vs baseline: 1.1039x; 1.1039x over previous
//
#include <hip/hip_runtime.h>
#include <stdint.h>
#include <math.h>

#define NB      8
#define NPTS    16384
#define NPOINT  512
#define NCH     128
#define KNBR    32
#define R2      0.04f

typedef unsigned long long u64;

// argmax step over (value desc, index asc) using DPP permute (VALU latency)
#define DPP_ARG_STEP(v, p, CTRL) do {                                          \
    float _ov = __builtin_bit_cast(float, __builtin_amdgcn_update_dpp(         \
        __builtin_bit_cast(int, (v)), __builtin_bit_cast(int, (v)),            \
        (CTRL), 0xF, 0xF, false));                                             \
    int _op = __builtin_amdgcn_update_dpp((p), (p), (CTRL), 0xF, 0xF, false);  \
    bool _t = (_ov > (v)) || ((_ov == (v)) && (_op < (p)));                    \
    (v) = _t ? _ov : (v);                                                      \
    (p) = _t ? _op : (p);                                                      \
} while (0)

#define SHFL_ARG_STEP(v, p, XORAMT) do {                                       \
    float _ov = __shfl_xor((v), (XORAMT), 64);                                 \
    int   _op = __shfl_xor((p), (XORAMT), 64);                                 \
    bool _t = (_ov > (v)) || ((_ov == (v)) && (_op < (p)));                    \
    (v) = _t ? _ov : (v);                                                      \
    (p) = _t ? _op : (p);                                                      \
} while (0)

// -------- kernel 0: per-batch morton counting sort --------------------------
// Sorts points by 9-bit morton cell (8x8x8) into ws arrays sx/sy/sz/sidx.
// Within-cell order is arbitrary (LDS atomics); exactness of FPS does not
// depend on it because the argmax comparator tie-breaks on ORIGINAL index.
__global__ __launch_bounds__(1024, 4)
void sort_kernel(const float* __restrict__ xyz,
                 float* __restrict__ sx, float* __restrict__ sy,
                 float* __restrict__ sz, int* __restrict__ sidx)
{
    const int b = blockIdx.x;
    const int tid = threadIdx.x;
    const float* xb = xyz + (size_t)b * NPTS * 3;
    __shared__ int offs[512];
    if (tid < 512) offs[tid] = 0;
    __syncthreads();
    // pass 1: histogram
#pragma unroll
    for (int k = 0; k < 16; ++k) {
        int p = k * 1024 + tid;
        float x = xb[p * 3 + 0], y = xb[p * 3 + 1], z = xb[p * 3 + 2];
        int ix = (int)(x * 8.f); ix = ix < 0 ? 0 : (ix > 7 ? 7 : ix);
        int iy = (int)(y * 8.f); iy = iy < 0 ? 0 : (iy > 7 ? 7 : iy);
        int iz = (int)(z * 8.f); iz = iz < 0 ? 0 : (iz > 7 ? 7 : iz);
        int m = 0;
#pragma unroll
        for (int j = 0; j < 3; ++j)
            m |= ((ix >> j & 1) << (3 * j + 2)) | ((iy >> j & 1) << (3 * j + 1))
               | ((iz >> j & 1) << (3 * j));
        atomicAdd(&offs[m], 1);
    }
    __syncthreads();
    // exclusive prefix over 512 cells: wave 0, 8 cells/lane
    if (tid < 64) {
        int base = tid * 8, run = 0, v[8];
#pragma unroll
        for (int j = 0; j < 8; ++j) { v[j] = run; run += offs[base + j]; }
        int own = run;
        for (int off = 1; off < 64; off <<= 1) {
            int t = __shfl_up(run, off, 64);
            if (tid >= off) run += t;
        }
        int lane_excl = run - own;
#pragma unroll
        for (int j = 0; j < 8; ++j) offs[base + j] = lane_excl + v[j];
    }
    __syncthreads();
    // pass 2: scatter (recompute cell; slot via LDS atomic)
    float* sxb = sx + (size_t)b * NPTS;
    float* syb = sy + (size_t)b * NPTS;
    float* szb = sz + (size_t)b * NPTS;
    int*   sib = sidx + (size_t)b * NPTS;
#pragma unroll
    for (int k = 0; k < 16; ++k) {
        int p = k * 1024 + tid;
        float x = xb[p * 3 + 0], y = xb[p * 3 + 1], z = xb[p * 3 + 2];
        int ix = (int)(x * 8.f); ix = ix < 0 ? 0 : (ix > 7 ? 7 : ix);
        int iy = (int)(y * 8.f); iy = iy < 0 ? 0 : (iy > 7 ? 7 : iy);
        int iz = (int)(z * 8.f); iz = iz < 0 ? 0 : (iz > 7 ? 7 : iz);
        int m = 0;
#pragma unroll
        for (int j = 0; j < 3; ++j)
            m |= ((ix >> j & 1) << (3 * j + 2)) | ((iy >> j & 1) << (3 * j + 1))
               | ((iz >> j & 1) << (3 * j));
        int pos = atomicAdd(&offs[m], 1);
        sxb[pos] = x; syb[pos] = y; szb[pos] = z; sib[pos] = p;
    }
}

// -------- kernel 1: FPS with exact wave-skip (blocks 0..7) + transpose ------
// Each of 16 waves owns 1024 morton-contiguous points (16/thread) with a
// bounding box. Per iteration: if min-sqdist(centroid, box) with conservative
// margin >= wave's cached max dist, the min-update provably changes nothing
// (bit-exact) and the whole wave skips; else full update + wave argmax.
// Comparators tie-break on ORIGINAL index at every level (sorted layout
// destroys the index ordering the reference relies on).
__global__
__attribute__((amdgpu_flat_work_group_size(1024, 1024)))
__attribute__((amdgpu_waves_per_eu(4, 4)))
void fps_transpose_kernel(const float* __restrict__ xyz,
                          const float* __restrict__ sx,
                          const float* __restrict__ sy,
                          const float* __restrict__ sz,
                          const int* __restrict__ sidx,
                          const float* __restrict__ feat,
                          float* __restrict__ out,     // new_xyz at [0,12288)
                          int* __restrict__ cent,      // ws: 8*512 ints
                          float* __restrict__ ft,      // ws: (B,N,128) fp32
                          int use_ft)
{
    const int blk = blockIdx.x;
    const int tid = threadIdx.x;

    if (blk < NB) {
        const int b = blk;
        const float* xb = xyz + (size_t)b * NPTS * 3;
        const size_t sb = (size_t)b * NPTS;
        const int lane = tid & 63;
        const int wid  = tid >> 6;

        float px[16], py[16], pz[16], dist[16];
        int   pid[16];
#pragma unroll
        for (int k = 0; k < 16; ++k) {
            int p = wid * 1024 + k * 64 + lane;   // wave-contiguous sorted pts
            px[k] = sx[sb + p];
            py[k] = sy[sb + p];
            pz[k] = sz[sb + p];
            pid[k] = sidx[sb + p];
            dist[k] = 1e10f;
        }
        // wave bounding box (exact fp32 min/max of member coords)
        float lox = px[0], hix = px[0], loy = py[0], hiy = py[0];
        float loz = pz[0], hiz = pz[0];
#pragma unroll
        for (int k = 1; k < 16; ++k) {
            lox = fminf(lox, px[k]); hix = fmaxf(hix, px[k]);
            loy = fminf(loy, py[k]); hiy = fmaxf(hiy, py[k]);
            loz = fminf(loz, pz[k]); hiz = fmaxf(hiz, pz[k]);
        }
        for (int off = 1; off < 64; off <<= 1) {
            lox = fminf(lox, __shfl_xor(lox, off, 64));
            hix = fmaxf(hix, __shfl_xor(hix, off, 64));
            loy = fminf(loy, __shfl_xor(loy, off, 64));
            hiy = fmaxf(hiy, __shfl_xor(hiy, off, 64));
            loz = fminf(loz, __shfl_xor(loz, off, 64));
            hiz = fmaxf(hiz, __shfl_xor(hiz, off, 64));
        }

        __shared__ float s_v[2][16];
        __shared__ int   s_p[2][16];

        float cbv = 1e10f;        // cached wave max dist (exact)
        int   cbp = 0x7FFFFFFF;   // cached wave argmax (orig idx)
        float cx = xb[0], cy = xb[1], cz = xb[2];
        if (tid == 0) {
            cent[b * NPOINT + 0] = 0;
            out[((size_t)b * NPOINT + 0) * 3 + 0] = cx;
            out[((size_t)b * NPOINT + 0) * 3 + 1] = cy;
            out[((size_t)b * NPOINT + 0) * 3 + 2] = cz;
        }

        for (int i = 1; i < NPOINT; ++i) {
            // conservative lower bound of d_ref(p, c) over the wave box
            float gx = fmaxf(fmaxf(__fsub_rn(lox, cx), __fsub_rn(cx, hix)), 0.f);
            float gy = fmaxf(fmaxf(__fsub_rn(loy, cy), __fsub_rn(cy, hiy)), 0.f);
            float gz = fmaxf(fmaxf(__fsub_rn(loz, cz), __fsub_rn(cz, hiz)), 0.f);
            float lb = gx * gx + gy * gy + gz * gz;
            // margin 5e-6 rel covers all fp32 rounding between lb and d_ref
            if (!(lb * 0.999995f >= cbv)) {       // wave-uniform branch
                float bv = -1.0f; int bp = 0x7FFFFFFF;
#pragma unroll
                for (int k = 0; k < 16; ++k) {
                    float dx = __fsub_rn(px[k], cx);
                    float dy = __fsub_rn(py[k], cy);
                    float dz = __fsub_rn(pz[k], cz);
                    float d  = __fadd_rn(__fadd_rn(__fmul_rn(dx, dx),
                                                   __fmul_rn(dy, dy)),
                                         __fmul_rn(dz, dz));
                    float nd = fminf(dist[k], d);   // np.minimum, exact
                    dist[k] = nd;
                    bool t = (nd > bv) || ((nd == bv) && (pid[k] < bp));
                    bv = t ? nd : bv;
                    bp = t ? pid[k] : bp;
                }
                DPP_ARG_STEP(bv, bp, 0xB1);
                DPP_ARG_STEP(bv, bp, 0x4E);
                DPP_ARG_STEP(bv, bp, 0x141);
                DPP_ARG_STEP(bv, bp, 0x140);
                SHFL_ARG_STEP(bv, bp, 16);
                SHFL_ARG_STEP(bv, bp, 32);
                cbv = bv; cbp = bp;   // uniform across wave after reduction
            }
            const int buf = i & 1;
            if (lane == 0) { s_v[buf][wid] = cbv; s_p[buf][wid] = cbp; }
            __syncthreads();   // double-buffered: one barrier per iteration
            float fv = s_v[buf][lane & 15];
            int   fp = s_p[buf][lane & 15];
            DPP_ARG_STEP(fv, fp, 0xB1);
            DPP_ARG_STEP(fv, fp, 0x4E);
            DPP_ARG_STEP(fv, fp, 0x141);
            DPP_ARG_STEP(fv, fp, 0x140);
            const int cur = __builtin_amdgcn_readfirstlane(fp);
            cx = xb[cur * 3 + 0];   // uniform reload, L2-hot
            cy = xb[cur * 3 + 1];
            cz = xb[cur * 3 + 2];
            if (tid == 0) {
                cent[b * NPOINT + i] = cur;
                size_t o = ((size_t)b * NPOINT + i) * 3;
                out[o + 0] = cx; out[o + 1] = cy; out[o + 2] = cz;
            }
        }
    } else {
        if (!use_ft) return;
        // transpose feat (B,128,N) -> ft (B,N,128), 32x32 tiles, 1024 thr
        int t  = blk - NB;
        int b  = t >> 11;          // 2048 tiles per batch
        int r  = t & 2047;
        int ct = r >> 9;           // channel tile (4)
        int nt = r & 511;          // point tile (512)
        __shared__ float tile[32][33];
        int tx = tid & 31, ty = tid >> 5;
        int c = ct * 32 + ty, n = nt * 32 + tx;
        tile[ty][tx] = feat[((size_t)b * NCH + c) * NPTS + n];
        __syncthreads();
        int n2 = nt * 32 + ty, c2 = ct * 32 + tx;
        ft[((size_t)b * NPTS + n2) * NCH + c2] = tile[tx][ty];
    }
}

// -------- kernel 2: ball query + grouped max pool ---------------------------
__global__ __launch_bounds__(256, 4)
void query_pool_kernel(const float* __restrict__ xyz,
                       const float* __restrict__ feat,
                       const float* __restrict__ ft,
                       const int* __restrict__ cent,
                       float* __restrict__ out_sub,   // (B,128,512)
                       int use_ft)
{
    const int tid  = threadIdx.x;
    const int widx = tid >> 6;
    const int lane = tid & 63;
    const int w = blockIdx.x * 4 + widx;   // 0..4095
    const int b = w >> 9;
    const int s = w & 511;

    const float* xb = xyz + (size_t)b * NPTS * 3;
    const int ci = cent[b * NPOINT + s];
    const float sxc = xb[ci * 3 + 0];
    const float syc = xb[ci * 3 + 1];
    const float szc = xb[ci * 3 + 2];
    const float snorm = __fadd_rn(__fadd_rn(__fmul_rn(sxc, sxc),
                                            __fmul_rn(syc, syc)),
                                  __fmul_rn(szc, szc));

    __shared__ int lidx[4][KNBR];
    int found = 0;
    for (int base = 0; base < NPTS && found < KNBR; base += 64) {
        int j = base + lane;
        float dx = xb[j * 3 + 0];
        float dy = xb[j * 3 + 1];
        float dz = xb[j * 3 + 2];
        float dn = __fadd_rn(__fadd_rn(__fmul_rn(dx, dx),
                                       __fmul_rn(dy, dy)),
                             __fmul_rn(dz, dz));
        float dot = __fadd_rn(__fadd_rn(__fmul_rn(sxc, dx),
                                        __fmul_rn(syc, dy)),
                              __fmul_rn(szc, dz));
        float d = __fadd_rn(__fadd_rn(__fmul_rn(-2.0f, dot), snorm), dn);
        bool inball = !(d > R2);
        unsigned long long mask = __ballot(inball);
        int before = (int)__popcll(mask & ((1ULL << lane) - 1ULL));
        int slot = found + before;
        if (inball && slot < KNBR) lidx[widx][slot] = j;
        found += (int)__popcll(mask);
    }
    int cnt = found < KNBR ? found : KNBR;   // cnt >= 1 (self in ball)
    __syncthreads();

    float a0 = -INFINITY, a1 = -INFINITY;
    if (use_ft) {
        for (int m = 0; m < cnt; ++m) {
            int i = lidx[widx][m];
            const float* row = ft + ((size_t)b * NPTS + i) * NCH;
            a0 = fmaxf(a0, row[lane]);
            a1 = fmaxf(a1, row[lane + 64]);
        }
    } else {
        for (int m = 0; m < cnt; ++m) {
            int i = lidx[widx][m];
            a0 = fmaxf(a0, feat[((size_t)b * NCH + lane) * NPTS + i]);
            a1 = fmaxf(a1, feat[((size_t)b * NCH + lane + 64) * NPTS + i]);
        }
    }
    out_sub[((size_t)b * NCH + lane) * NPOINT + s] = a0;
    out_sub[((size_t)b * NCH + lane + 64) * NPOINT + s] = a1;
}

extern "C" void kernel_launch(void* const* d_in, const int* in_sizes, int n_in,
                              void* d_out, int out_size, void* d_ws, size_t ws_size,
                              hipStream_t stream)
{
    const float* xyz  = (const float*)d_in[0];   // (8,16384,3)
    const float* feat = (const float*)d_in[1];   // (8,128,16384)
    float* out = (float*)d_out;                  // [new_xyz | sub_features]

    const size_t NBP = (size_t)NB * NPTS;        // 131072
    char* w = (char*)d_ws;
    int*   cent = (int*)w;                        w += 16384;        // 16 KB
    float* sx   = (float*)w;                      w += NBP * 4;      // 512 KB
    float* sy   = (float*)w;                      w += NBP * 4;
    float* sz   = (float*)w;                      w += NBP * 4;
    int*   sidx = (int*)w;                        w += NBP * 4;
    float* ft   = (float*)w;                                          // 67 MB
    const size_t need_ft = (size_t)(w - (char*)d_ws) + NBP * NCH * 4ull;
    int use_ft = (ws_size >= need_ft) ? 1 : 0;

    hipLaunchKernelGGL(sort_kernel, dim3(NB), dim3(1024), 0, stream,
                       xyz, sx, sy, sz, sidx);

    int nblocks1 = NB + (use_ft ? NB * (NCH / 32) * (NPTS / 32) : 0);
    hipLaunchKernelGGL(fps_transpose_kernel, dim3(nblocks1), dim3(1024), 0, stream,
                       xyz, sx, sy, sz, sidx, feat, out, cent, ft, use_ft);

    hipLaunchKernelGGL(query_pool_kernel, dim3((NB * NPOINT) / 4), dim3(256), 0, stream,
                       xyz, feat, ft, cent, out + (size_t)NB * NPOINT * 3, use_ft);
}